// Round 20
// baseline (800.407 us; speedup 1.0000x reference)
//
#include <hip/hip_runtime.h>
#include <hip/hip_bf16.h>

#define VOCAB 32000
#define EMBED 512
#define HIDDEN 1024
#define NB 8
#define NT 256
#define XH_ROWS 16

#define NCH 8
#define NMEM 32
#define RCOLS 32
#define NBLK_REC 256
#define NBLK_TR 128
#define TILES_PER_TR 250

typedef __attribute__((ext_vector_type(8))) short bf16x8;
typedef __attribute__((ext_vector_type(4))) float f32x4;
typedef __attribute__((ext_vector_type(4))) unsigned u32x4;

#define AS1 __attribute__((address_space(1)))
#define AS3 __attribute__((address_space(3)))

__device__ __forceinline__ unsigned short bf16_bits(float f) {
    __hip_bfloat16 b = __float2bfloat16(f);
    unsigned short s;
    __builtin_memcpy(&s, &b, 2);
    return s;
}
__device__ __forceinline__ float lo16f(unsigned u) { return __uint_as_float(u << 16); }
__device__ __forceinline__ float hi16f(unsigned u) { return __uint_as_float(u & 0xffff0000u); }

// ---------------- xh = emb[x] @ W_xh + b_h  (fp32) ----------------
__global__ __launch_bounds__(256) void k_xh(const int* __restrict__ ids,
                                            const float* __restrict__ emb,
                                            const float* __restrict__ Wxh,
                                            const float* __restrict__ bh,
                                            float* __restrict__ xh) {
    __shared__ alignas(16) float embS[XH_ROWS][EMBED];
    __shared__ int idsS[XH_ROWS];
    const int tid = threadIdx.x;
    const int blk = blockIdx.x;
    if (tid < XH_ROWS) idsS[tid] = ids[blk * XH_ROWS + tid];
    __syncthreads();
    const float4* emb4 = (const float4*)emb;
#pragma unroll
    for (int rep = 0; rep < (XH_ROWS * EMBED / 4) / 256; ++rep) {
        const int lin = rep * 256 + tid;
        const int r = lin >> 7;
        const int e4 = lin & 127;
        *(float4*)&embS[r][e4 * 4] = emb4[(size_t)idsS[r] * (EMBED / 4) + e4];
    }
    __syncthreads();
    float4 acc[XH_ROWS] = {};
    const float4* W4 = (const float4*)Wxh;
    for (int e = 0; e < EMBED; ++e) {
        const float4 w = W4[(size_t)e * (HIDDEN / 4) + tid];
#pragma unroll
        for (int r = 0; r < XH_ROWS; ++r) {
            const float ev = embS[r][e];
            acc[r].x += ev * w.x; acc[r].y += ev * w.y;
            acc[r].z += ev * w.z; acc[r].w += ev * w.w;
        }
    }
    const float4 bv = ((const float4*)bh)[tid];
#pragma unroll
    for (int r = 0; r < XH_ROWS; ++r) {
        float4 o;
        o.x = acc[r].x + bv.x; o.y = acc[r].y + bv.y;
        o.z = acc[r].z + bv.z; o.w = acc[r].w + bv.w;
        ((float4*)xh)[(size_t)(blk * XH_ROWS + r) * (HIDDEN / 4) + tid] = o;
    }
}

// ---------------- fused persistent recurrence + W_hy transpose ----------------
// rec exchange this round: u32 token-in-data (h<<16 | tok), ONE dwordx4 poll per
// thread (4 self-describing u32s) -> half the poll transactions, single-RTT detect.
// Fast path: asm global_load_dwordx4 sc0 sc1 (device-coherent); bounded fallback to
// known-good __hip_atomic_load after 32 tries (no-hang guarantee).
__global__ __launch_bounds__(256, 1) void k_fused(const float* __restrict__ Whh,
                                                  const float* __restrict__ xh,
                                                  unsigned* __restrict__ hxU,
                                                  __hip_bfloat16* __restrict__ hs,
                                                  const float* __restrict__ Why,
                                                  __hip_bfloat16* __restrict__ Wt) {
    __shared__ alignas(16) float smemF[9808];
    float* xhS = smemF;
    float* hS  = smemF + 8192;
    float* red = smemF + 9280;
    const int tid = threadIdx.x;
    const int bid = blockIdx.x;

    if (bid >= NBLK_REC) {
        // ---- transpose role: 8 tiles (32x33 f32) per round ----
        const int tb = bid - NBLK_REC;
        const int cc = tid & 31;
        const int r0 = tid >> 5;
        const int tbase = tb * TILES_PER_TR;
        for (int rnd = 0; rnd < (TILES_PER_TR + 7) / 8; ++rnd) {
            const int base = rnd * 8;
            __syncthreads();
#pragma unroll
            for (int u = 0; u < 8; ++u) {
                const int i = base + u;
                if (i < TILES_PER_TR) {
                    const int g = tbase + i;
                    const int n0 = (g % 1000) * 32;
                    const int k0 = (g / 1000) * 32;
                    float* tile = smemF + u * 1056;
#pragma unroll
                    for (int rr = 0; rr < 4; ++rr) {
                        const int r = r0 + rr * 8;
                        tile[cc * 33 + r] = Why[(size_t)(k0 + r) * VOCAB + n0 + cc];
                    }
                }
            }
            __syncthreads();
#pragma unroll
            for (int u = 0; u < 8; ++u) {
                const int i = base + u;
                if (i < TILES_PER_TR) {
                    const int g = tbase + i;
                    const int n0 = (g % 1000) * 32;
                    const int k0 = (g / 1000) * 32;
                    float* tile = smemF + u * 1056;
#pragma unroll
                    for (int rr = 0; rr < 4; ++rr) {
                        const int n = r0 + rr * 8;
                        Wt[(size_t)(n0 + n) * HIDDEN + k0 + cc] = __float2bfloat16(tile[n * 33 + cc]);
                    }
                }
            }
        }
        return;
    }

    // ---- recurrence role ----
    const int c = bid & (NCH - 1);
    const int m = bid >> 3;
    const int j0 = m * RCOLS;
    unsigned* hxc = hxU + (size_t)c * 2048;   // [2][1024] u32 words

    // h_{-1}=0 token 0 in buf1 (this member's 32 words)
    if (tid < RCOLS)
        __hip_atomic_store(&hxc[1024 + j0 + tid], 0u, __ATOMIC_RELAXED,
                           __HIP_MEMORY_SCOPE_AGENT);

    const int col2 = tid & 15;
    const int part = tid >> 4;

    u32x4 wreg[16];
#pragma unroll
    for (int j = 0; j < 16; ++j) {
        u32x4 q;
#pragma unroll
        for (int e = 0; e < 4; ++e) {
            const int i = part * 64 + 4 * j + e;
            const float2 wv = *(const float2*)&Whh[(size_t)i * HIDDEN + j0 + 2 * col2];
            q[e] = (unsigned)bf16_bits(wv.x) | ((unsigned)bf16_bits(wv.y) << 16);
        }
        wreg[j] = q;
    }
    for (int idx = tid; idx < NT * RCOLS; idx += 256) {
        const int t = idx >> 5;
        const int col = idx & 31;
        xhS[idx] = xh[(size_t)(c * NT + t) * HIDDEN + j0 + col];
    }
    __syncthreads();

    const f32x4* hv4 = (const f32x4*)&hS[part * 68];
    const int idx4 = 4 * tid;                      // this thread's 4 u32 words
    const int pe0 = 4 * tid + 4 * (tid >> 4);      // padded hS index (same 64-block)

    for (int t = 0; t < NT; ++t) {
        const unsigned* rb = hxc + ((t + 1) & 1) * 1024 + idx4;  // h_{t-1}, tokens == t
        unsigned* wb = hxc + (t & 1) * 1024;                     // write h_t, token t+1
        const unsigned tok = (unsigned)t;
        u32x4 q;
        asm volatile("global_load_dwordx4 %0, %1, off sc0 sc1\n\ts_waitcnt vmcnt(0)"
                     : "=v"(q) : "v"(rb) : "memory");
        int tries = 0;
        while (((q.x & 0xffffu) != tok) | ((q.y & 0xffffu) != tok) |
               ((q.z & 0xffffu) != tok) | ((q.w & 0xffffu) != tok)) {
            ++tries;
            if (tries < 32) {
                asm volatile("global_load_dwordx4 %0, %1, off sc0 sc1\n\ts_waitcnt vmcnt(0)"
                             : "=v"(q) : "v"(rb) : "memory");
            } else {
                __builtin_amdgcn_s_sleep(1);
                q.x = __hip_atomic_load(rb + 0, __ATOMIC_RELAXED, __HIP_MEMORY_SCOPE_AGENT);
                q.y = __hip_atomic_load(rb + 1, __ATOMIC_RELAXED, __HIP_MEMORY_SCOPE_AGENT);
                q.z = __hip_atomic_load(rb + 2, __ATOMIC_RELAXED, __HIP_MEMORY_SCOPE_AGENT);
                q.w = __hip_atomic_load(rb + 3, __ATOMIC_RELAXED, __HIP_MEMORY_SCOPE_AGENT);
            }
        }
        float4 hv;
        hv.x = __uint_as_float(q.x & 0xffff0000u);
        hv.y = __uint_as_float(q.y & 0xffff0000u);
        hv.z = __uint_as_float(q.z & 0xffff0000u);
        hv.w = __uint_as_float(q.w & 0xffff0000u);
        *(float4*)&hS[pe0] = hv;
        __syncthreads();
        float a0 = 0.f, a1 = 0.f;
#pragma unroll
        for (int j = 0; j < 16; ++j) {
            const u32x4 w4 = wreg[j];
            const f32x4 h4 = hv4[j];
            a0 = fmaf(lo16f(w4.x), h4.x, a0); a1 = fmaf(hi16f(w4.x), h4.x, a1);
            a0 = fmaf(lo16f(w4.y), h4.y, a0); a1 = fmaf(hi16f(w4.y), h4.y, a1);
            a0 = fmaf(lo16f(w4.z), h4.z, a0); a1 = fmaf(hi16f(w4.z), h4.z, a1);
            a0 = fmaf(lo16f(w4.w), h4.w, a0); a1 = fmaf(hi16f(w4.w), h4.w, a1);
        }
        red[part * 33 + 2 * col2]     = a0;
        red[part * 33 + 2 * col2 + 1] = a1;
        __syncthreads();
        if (tid < RCOLS) {
            float s = 0.f;
#pragma unroll
            for (int p = 0; p < 16; ++p) s += red[p * 33 + tid];
            const float v = tanhf(xhS[t * RCOLS + tid] + s);
            const unsigned hb = (unsigned)bf16_bits(v);
            ((unsigned short*)hs)[(size_t)(c * NT + t) * HIDDEN + j0 + tid] = (unsigned short)hb;
            __hip_atomic_store(&wb[j0 + tid], (hb << 16) | (unsigned)(t + 1),
                               __ATOMIC_RELAXED, __HIP_MEMORY_SCOPE_AGENT);
        }
        // no trailing barrier: next poll gates on this block's own production
    }
}

// ---------------- y = hs @ Wt^T + b_y : r19 8-phase (kept; passed, ~245us) ----------------
__global__ __launch_bounds__(512, 2) void k_proj(const unsigned short* __restrict__ A,
                                                 const unsigned short* __restrict__ Bt,
                                                 const float* __restrict__ by,
                                                 float* __restrict__ C) {
    __shared__ unsigned short LDSu[8 * 8192];
    const int tid = threadIdx.x;
    const int wid = tid >> 6;
    const int lane = tid & 63;
    const int lin = blockIdx.x;
    const int swz = (lin & 7) * 125 + (lin >> 3);
    const int mt = swz & 7, nt = swz >> 3;
    const int m0 = mt * 256, n0 = nt * 256;
    const int wr = wid >> 2, wc = wid & 3;
    const int fr = lane & 15, fq = lane >> 4;

    f32x4 acc[8][4] = {};
    bf16x8 af[2][4][2];
    bf16x8 bg[2][2][2];

#define VMC0   asm volatile("s_waitcnt vmcnt(0)" ::: "memory")
#define LGKM0  do { asm volatile("s_waitcnt lgkmcnt(0)" ::: "memory"); \
                    __builtin_amdgcn_sched_barrier(0); } while (0)
#define BAR    __builtin_amdgcn_s_barrier()

#define STAGE_HALF(SRC, ROW0, KT, B_, MAT, H)                                             \
    do {                                                                                  \
        const unsigned short* g_ = (SRC) + (size_t)((ROW0) + (H) * 128) * HIDDEN + (KT) * 64; \
        _Pragma("unroll")                                                                 \
        for (int s2 = 0; s2 < 2; ++s2) {                                                  \
            const int ch_ = s2 * 512 + tid;                                               \
            const int lr_ = ch_ >> 3, sp_ = ch_ & 7;                                      \
            const int gs_ = sp_ ^ (lr_ & 7);                                              \
            __builtin_amdgcn_global_load_lds(                                             \
                (const AS1 unsigned*)(g_ + (size_t)lr_ * HIDDEN + gs_ * 8),               \
                (AS3 unsigned*)(LDSu + ((B_) * 4 + (MAT) * 2 + (H)) * 8192                \
                                + (s2 * 512 + wid * 64) * 8), 16, 0, 0);                  \
        }                                                                                 \
    } while (0)

#define READ_AF(B_, MH)                                                                   \
    do {                                                                                  \
        const unsigned short* r_ = LDSu + ((B_) * 4 + wr) * 8192;                         \
        _Pragma("unroll")                                                                 \
        for (int q_ = 0; q_ < 4; ++q_) {                                                  \
            const int lr_ = ((MH) * 4 + q_) * 16 + fr;                                    \
            _Pragma("unroll")                                                             \
            for (int ks_ = 0; ks_ < 2; ++ks_)                                             \
                af[MH][q_][ks_] = *(const bf16x8*)&r_[lr_ * 64 + (((ks_ * 4 + fq) ^ (fr & 7)) * 8)]; \
        }                                                                                 \
    } while (0)

#define READ_BG(B_, NH)                                                                   \
    do {                                                                                  \
        const unsigned short* r_ = LDSu + ((B_) * 4 + 2 + (wc >> 1)) * 8192;              \
        _Pragma("unroll")                                                                 \
        for (int j_ = 0; j_ < 2; ++j_) {                                                  \
            const int lr_ = (wc & 1) * 64 + ((NH) * 2 + j_) * 16 + fr;                    \
            _Pragma("unroll")                                                             \
            for (int ks_ = 0; ks_ < 2; ++ks_)                                             \
                bg[NH][j_][ks_] = *(const bf16x8*)&r_[lr_ * 64 + (((ks_ * 4 + fq) ^ (fr & 7)) * 8)]; \
        }                                                                                 \
    } while (0)

#define MFMA16(MH, NH)                                                                    \
    do {                                                                                  \
        __builtin_amdgcn_s_setprio(1);                                                    \
        _Pragma("unroll")                                                                 \
        for (int q_ = 0; q_ < 4; ++q_)                                                    \
            _Pragma("unroll")                                                             \
            for (int j_ = 0; j_ < 2; ++j_) {                                              \
                acc[(MH) * 4 + q_][(NH) * 2 + j_] = __builtin_amdgcn_mfma_f32_16x16x32_bf16( \
                    af[MH][q_][0], bg[NH][j_][0], acc[(MH) * 4 + q_][(NH) * 2 + j_], 0, 0, 0); \
                acc[(MH) * 4 + q_][(NH) * 2 + j_] = __builtin_amdgcn_mfma_f32_16x16x32_bf16( \
                    af[MH][q_][1], bg[NH][j_][1], acc[(MH) * 4 + q_][(NH) * 2 + j_], 0, 0, 0); \
            }                                                                             \
        __builtin_amdgcn_s_setprio(0);                                                    \
    } while (0)

    STAGE_HALF(Bt, n0, 0, 0, 1, 0);
    STAGE_HALF(Bt, n0, 0, 0, 1, 1);
    STAGE_HALF(A,  m0, 0, 0, 0, 0);
    STAGE_HALF(A,  m0, 0, 0, 0, 1);
    STAGE_HALF(Bt, n0, 1, 1, 1, 0);
    VMC0;
    BAR;

    for (int i = 0; i < 8; ++i) {
        const int t_b1cur = 2 * i + 1;
        const int t_b0nxt = 2 * i + 2;
        const int t_b1nxt = 2 * i + 3;
        READ_AF(0, 0); READ_BG(0, 0);
        STAGE_HALF(Bt, n0, t_b1cur, 1, 1, 1);
        BAR; LGKM0; MFMA16(0, 0); BAR;
        READ_BG(0, 1);
        STAGE_HALF(A, m0, t_b1cur, 1, 0, 0);
        BAR; LGKM0; MFMA16(0, 1); BAR;
        READ_AF(0, 1);
        STAGE_HALF(A, m0, t_b1cur, 1, 0, 1);
        BAR; LGKM0; MFMA16(1, 0); BAR;
        VMC0;
        if (t_b0nxt < 16) STAGE_HALF(Bt, n0, t_b0nxt, 0, 1, 0);
        BAR; MFMA16(1, 1); BAR;
        READ_AF(1, 0); READ_BG(1, 0);
        if (t_b0nxt < 16) STAGE_HALF(Bt, n0, t_b0nxt, 0, 1, 1);
        BAR; LGKM0; MFMA16(0, 0); BAR;
        READ_BG(1, 1);
        if (t_b0nxt < 16) STAGE_HALF(A, m0, t_b0nxt, 0, 0, 0);
        BAR; LGKM0; MFMA16(0, 1); BAR;
        READ_AF(1, 1);
        if (t_b0nxt < 16) STAGE_HALF(A, m0, t_b0nxt, 0, 0, 1);
        BAR; LGKM0; MFMA16(1, 0); BAR;
        VMC0;
        if (t_b1nxt < 16) STAGE_HALF(Bt, n0, t_b1nxt, 1, 1, 0);
        BAR; MFMA16(1, 1); BAR;
    }

#undef VMC0
#undef LGKM0
#undef BAR
#undef STAGE_HALF
#undef READ_AF
#undef READ_BG
#undef MFMA16

#pragma unroll
    for (int ni = 0; ni < 4; ++ni) {
        const int col = n0 + wc * 64 + ni * 16 + fr;
        const float bias = by[col];
#pragma unroll
        for (int mi = 0; mi < 8; ++mi) {
            const int row = m0 + wr * 128 + mi * 16 + fq * 4;
            float* cp = C + (size_t)row * VOCAB + col;
            cp[0]                 = acc[mi][ni][0] + bias;
            cp[(size_t)VOCAB]     = acc[mi][ni][1] + bias;
            cp[(size_t)2 * VOCAB] = acc[mi][ni][2] + bias;
            cp[(size_t)3 * VOCAB] = acc[mi][ni][3] + bias;
        }
    }
}

extern "C" void kernel_launch(void* const* d_in, const int* in_sizes, int n_in,
                              void* d_out, int out_size, void* d_ws, size_t ws_size,
                              hipStream_t stream) {
    const int*   x   = (const int*)d_in[0];
    const float* emb = (const float*)d_in[1];
    const float* Wxh = (const float*)d_in[2];
    const float* Whh = (const float*)d_in[3];
    const float* bh  = (const float*)d_in[4];
    const float* Why = (const float*)d_in[5];
    const float* by  = (const float*)d_in[6];
    float* y = (float*)d_out;

    char* ws = (char*)d_ws;
    const size_t off_xh = 0;
    const size_t off_hx = off_xh + (size_t)NB * NT * HIDDEN * 4;
    const size_t off_hs = off_hx + (size_t)NCH * 2 * 1024 * 4;
    const size_t off_wt = off_hs + (size_t)NB * NT * HIDDEN * 2;
    const size_t need   = off_wt + (size_t)VOCAB * HIDDEN * 2;
    if (ws_size < need) return;

    float* xh = (float*)(ws + off_xh);
    unsigned* hxU = (unsigned*)(ws + off_hx);
    __hip_bfloat16* hs = (__hip_bfloat16*)(ws + off_hs);
    __hip_bfloat16* Wt = (__hip_bfloat16*)(ws + off_wt);

    k_xh<<<dim3((NB * NT) / XH_ROWS), 256, 0, stream>>>(x, emb, Wxh, bh, xh);
    k_fused<<<dim3(NBLK_REC + NBLK_TR), 256, 0, stream>>>(Whh, xh, hxU, hs, Why, Wt);
    k_proj<<<dim3((2048 / 256) * (VOCAB / 256)), 512, 0, stream>>>((const unsigned short*)hs,
                                                                   (const unsigned short*)Wt, by, y);
}

// Round 21
// 796.710 us; speedup vs baseline: 1.0046x; 1.0046x over previous
//
#include <hip/hip_runtime.h>
#include <hip/hip_bf16.h>

#define VOCAB 32000
#define EMBED 512
#define HIDDEN 1024
#define NB 8
#define NT 256
#define XH_ROWS 16

#define NCH 8
#define NMEM 32
#define RCOLS 32
#define NBLK_REC 256
#define NBLK_TR 128
#define TILES_PER_TR 250

typedef __attribute__((ext_vector_type(8))) short bf16x8;
typedef __attribute__((ext_vector_type(4))) float f32x4;
typedef __attribute__((ext_vector_type(4))) unsigned u32x4;

#define AS1 __attribute__((address_space(1)))
#define AS3 __attribute__((address_space(3)))

__device__ __forceinline__ unsigned short bf16_bits(float f) {
    __hip_bfloat16 b = __float2bfloat16(f);
    unsigned short s;
    __builtin_memcpy(&s, &b, 2);
    return s;
}
__device__ __forceinline__ float lo16f(unsigned u) { return __uint_as_float(u << 16); }
__device__ __forceinline__ float hi16f(unsigned u) { return __uint_as_float(u & 0xffff0000u); }

// ---------------- xh = emb[x] @ W_xh + b_h  (fp32) ----------------
__global__ __launch_bounds__(256) void k_xh(const int* __restrict__ ids,
                                            const float* __restrict__ emb,
                                            const float* __restrict__ Wxh,
                                            const float* __restrict__ bh,
                                            float* __restrict__ xh) {
    __shared__ alignas(16) float embS[XH_ROWS][EMBED];
    __shared__ int idsS[XH_ROWS];
    const int tid = threadIdx.x;
    const int blk = blockIdx.x;
    if (tid < XH_ROWS) idsS[tid] = ids[blk * XH_ROWS + tid];
    __syncthreads();
    const float4* emb4 = (const float4*)emb;
#pragma unroll
    for (int rep = 0; rep < (XH_ROWS * EMBED / 4) / 256; ++rep) {
        const int lin = rep * 256 + tid;
        const int r = lin >> 7;
        const int e4 = lin & 127;
        *(float4*)&embS[r][e4 * 4] = emb4[(size_t)idsS[r] * (EMBED / 4) + e4];
    }
    __syncthreads();
    float4 acc[XH_ROWS] = {};
    const float4* W4 = (const float4*)Wxh;
    for (int e = 0; e < EMBED; ++e) {
        const float4 w = W4[(size_t)e * (HIDDEN / 4) + tid];
#pragma unroll
        for (int r = 0; r < XH_ROWS; ++r) {
            const float ev = embS[r][e];
            acc[r].x += ev * w.x; acc[r].y += ev * w.y;
            acc[r].z += ev * w.z; acc[r].w += ev * w.w;
        }
    }
    const float4 bv = ((const float4*)bh)[tid];
#pragma unroll
    for (int r = 0; r < XH_ROWS; ++r) {
        float4 o;
        o.x = acc[r].x + bv.x; o.y = acc[r].y + bv.y;
        o.z = acc[r].z + bv.z; o.w = acc[r].w + bv.w;
        ((float4*)xh)[(size_t)(blk * XH_ROWS + r) * (HIDDEN / 4) + tid] = o;
    }
}

// ---------------- fused persistent recurrence + W_hy transpose (r12 protocol, best measured) ----------------
__global__ __launch_bounds__(256, 1) void k_fused(const float* __restrict__ Whh,
                                                  const float* __restrict__ xh,
                                                  unsigned long long* __restrict__ hx,
                                                  __hip_bfloat16* __restrict__ hs,
                                                  const float* __restrict__ Why,
                                                  __hip_bfloat16* __restrict__ Wt) {
    __shared__ alignas(16) float smemF[9808];
    float* xhS = smemF;
    float* hS  = smemF + 8192;
    float* red = smemF + 9280;
    const int tid = threadIdx.x;
    const int bid = blockIdx.x;

    if (bid >= NBLK_REC) {
        const int tb = bid - NBLK_REC;
        const int cc = tid & 31;
        const int r0 = tid >> 5;
        const int tbase = tb * TILES_PER_TR;
        for (int rnd = 0; rnd < (TILES_PER_TR + 7) / 8; ++rnd) {
            const int base = rnd * 8;
            __syncthreads();
#pragma unroll
            for (int u = 0; u < 8; ++u) {
                const int i = base + u;
                if (i < TILES_PER_TR) {
                    const int g = tbase + i;
                    const int n0 = (g % 1000) * 32;
                    const int k0 = (g / 1000) * 32;
                    float* tile = smemF + u * 1056;
#pragma unroll
                    for (int rr = 0; rr < 4; ++rr) {
                        const int r = r0 + rr * 8;
                        tile[cc * 33 + r] = Why[(size_t)(k0 + r) * VOCAB + n0 + cc];
                    }
                }
            }
            __syncthreads();
#pragma unroll
            for (int u = 0; u < 8; ++u) {
                const int i = base + u;
                if (i < TILES_PER_TR) {
                    const int g = tbase + i;
                    const int n0 = (g % 1000) * 32;
                    const int k0 = (g / 1000) * 32;
                    float* tile = smemF + u * 1056;
#pragma unroll
                    for (int rr = 0; rr < 4; ++rr) {
                        const int n = r0 + rr * 8;
                        Wt[(size_t)(n0 + n) * HIDDEN + k0 + cc] = __float2bfloat16(tile[n * 33 + cc]);
                    }
                }
            }
        }
        return;
    }

    const int c = bid & (NCH - 1);
    const int m = bid >> 3;
    const int j0 = m * RCOLS;
    unsigned long long* hxc = hx + (size_t)c * 1024;

    if (tid < 16)
        __hip_atomic_store(&hxc[512 + m * 16 + tid], 0ull, __ATOMIC_RELAXED,
                           __HIP_MEMORY_SCOPE_AGENT);

    const int col2 = tid & 15;
    const int part = tid >> 4;

    u32x4 wreg[16];
#pragma unroll
    for (int j = 0; j < 16; ++j) {
        u32x4 q;
#pragma unroll
        for (int e = 0; e < 4; ++e) {
            const int i = part * 64 + 4 * j + e;
            const float2 wv = *(const float2*)&Whh[(size_t)i * HIDDEN + j0 + 2 * col2];
            q[e] = (unsigned)bf16_bits(wv.x) | ((unsigned)bf16_bits(wv.y) << 16);
        }
        wreg[j] = q;
    }
    for (int idx = tid; idx < NT * RCOLS; idx += 256) {
        const int t = idx >> 5;
        const int col = idx & 31;
        xhS[idx] = xh[(size_t)(c * NT + t) * HIDDEN + j0 + col];
    }
    __syncthreads();

    const f32x4* hv4 = (const f32x4*)&hS[part * 68];
    const int w0 = tid;
    const int w1 = tid + 256;
    const int pe0 = 2 * tid + 4 * (tid >> 5);

    for (int t = 0; t < NT; ++t) {
        unsigned long long* rbuf = hxc + ((t + 1) & 1) * 512;
        unsigned long long* wbuf = hxc + (t & 1) * 512;
        const unsigned long long tok = (unsigned long long)(unsigned)t;
        unsigned long long a = __hip_atomic_load(&rbuf[w0], __ATOMIC_RELAXED, __HIP_MEMORY_SCOPE_AGENT);
        unsigned long long b = __hip_atomic_load(&rbuf[w1], __ATOMIC_RELAXED, __HIP_MEMORY_SCOPE_AGENT);
        while (((a & 0xffffull) != tok) | ((b & 0xffffull) != tok)) {
            __builtin_amdgcn_s_sleep(1);
            if ((a & 0xffffull) != tok)
                a = __hip_atomic_load(&rbuf[w0], __ATOMIC_RELAXED, __HIP_MEMORY_SCOPE_AGENT);
            if ((b & 0xffffull) != tok)
                b = __hip_atomic_load(&rbuf[w1], __ATOMIC_RELAXED, __HIP_MEMORY_SCOPE_AGENT);
        }
        *(float2*)&hS[pe0] = make_float2(__uint_as_float(((unsigned)(a >> 16) & 0xffffu) << 16),
                                         __uint_as_float(((unsigned)(a >> 32) & 0xffffu) << 16));
        *(float2*)&hS[pe0 + 544] = make_float2(__uint_as_float(((unsigned)(b >> 16) & 0xffffu) << 16),
                                               __uint_as_float(((unsigned)(b >> 32) & 0xffffu) << 16));
        __syncthreads();
        float a0 = 0.f, a1 = 0.f;
#pragma unroll
        for (int j = 0; j < 16; ++j) {
            const u32x4 w4 = wreg[j];
            const f32x4 h4 = hv4[j];
            a0 = fmaf(lo16f(w4.x), h4.x, a0); a1 = fmaf(hi16f(w4.x), h4.x, a1);
            a0 = fmaf(lo16f(w4.y), h4.y, a0); a1 = fmaf(hi16f(w4.y), h4.y, a1);
            a0 = fmaf(lo16f(w4.z), h4.z, a0); a1 = fmaf(hi16f(w4.z), h4.z, a1);
            a0 = fmaf(lo16f(w4.w), h4.w, a0); a1 = fmaf(hi16f(w4.w), h4.w, a1);
        }
        red[part * 33 + 2 * col2]     = a0;
        red[part * 33 + 2 * col2 + 1] = a1;
        __syncthreads();
        if (tid < RCOLS) {
            float s = 0.f;
#pragma unroll
            for (int p = 0; p < 16; ++p) s += red[p * 33 + tid];
            const float v = tanhf(xhS[t * RCOLS + tid] + s);
            const unsigned hb = (unsigned)bf16_bits(v);
            ((unsigned short*)hs)[(size_t)(c * NT + t) * HIDDEN + j0 + tid] = (unsigned short)hb;
            const unsigned pb = (unsigned)__shfl_xor((int)hb, 1, 64);
            if ((tid & 1) == 0) {
                const unsigned long long wv = (unsigned long long)(unsigned)(t + 1)
                                            | ((unsigned long long)hb << 16)
                                            | ((unsigned long long)pb << 32);
                __hip_atomic_store(&wbuf[m * 16 + (tid >> 1)], wv, __ATOMIC_RELAXED,
                                   __HIP_MEMORY_SCOPE_AGENT);
            }
        }
    }
}

// ---------------- y = hs @ Wt^T + b_y : 256x256 8-phase pipeline (r19, best measured) ----------------
__global__ __launch_bounds__(512, 2) void k_proj(const unsigned short* __restrict__ A,
                                                 const unsigned short* __restrict__ Bt,
                                                 const float* __restrict__ by,
                                                 float* __restrict__ C) {
    __shared__ unsigned short LDSu[8 * 8192];
    const int tid = threadIdx.x;
    const int wid = tid >> 6;
    const int lane = tid & 63;
    const int lin = blockIdx.x;
    const int swz = (lin & 7) * 125 + (lin >> 3);
    const int mt = swz & 7, nt = swz >> 3;
    const int m0 = mt * 256, n0 = nt * 256;
    const int wr = wid >> 2, wc = wid & 3;
    const int fr = lane & 15, fq = lane >> 4;

    f32x4 acc[8][4] = {};
    bf16x8 af[2][4][2];
    bf16x8 bg[2][2][2];

#define VMC0   asm volatile("s_waitcnt vmcnt(0)" ::: "memory")
#define LGKM0  do { asm volatile("s_waitcnt lgkmcnt(0)" ::: "memory"); \
                    __builtin_amdgcn_sched_barrier(0); } while (0)
#define BAR    __builtin_amdgcn_s_barrier()

#define STAGE_HALF(SRC, ROW0, KT, B_, MAT, H)                                             \
    do {                                                                                  \
        const unsigned short* g_ = (SRC) + (size_t)((ROW0) + (H) * 128) * HIDDEN + (KT) * 64; \
        _Pragma("unroll")                                                                 \
        for (int s2 = 0; s2 < 2; ++s2) {                                                  \
            const int ch_ = s2 * 512 + tid;                                               \
            const int lr_ = ch_ >> 3, sp_ = ch_ & 7;                                      \
            const int gs_ = sp_ ^ (lr_ & 7);                                              \
            __builtin_amdgcn_global_load_lds(                                             \
                (const AS1 unsigned*)(g_ + (size_t)lr_ * HIDDEN + gs_ * 8),               \
                (AS3 unsigned*)(LDSu + ((B_) * 4 + (MAT) * 2 + (H)) * 8192                \
                                + (s2 * 512 + wid * 64) * 8), 16, 0, 0);                  \
        }                                                                                 \
    } while (0)

#define READ_AF(B_, MH)                                                                   \
    do {                                                                                  \
        const unsigned short* r_ = LDSu + ((B_) * 4 + wr) * 8192;                         \
        _Pragma("unroll")                                                                 \
        for (int q_ = 0; q_ < 4; ++q_) {                                                  \
            const int lr_ = ((MH) * 4 + q_) * 16 + fr;                                    \
            _Pragma("unroll")                                                             \
            for (int ks_ = 0; ks_ < 2; ++ks_)                                             \
                af[MH][q_][ks_] = *(const bf16x8*)&r_[lr_ * 64 + (((ks_ * 4 + fq) ^ (fr & 7)) * 8)]; \
        }                                                                                 \
    } while (0)

#define READ_BG(B_, NH)                                                                   \
    do {                                                                                  \
        const unsigned short* r_ = LDSu + ((B_) * 4 + 2 + (wc >> 1)) * 8192;              \
        _Pragma("unroll")                                                                 \
        for (int j_ = 0; j_ < 2; ++j_) {                                                  \
            const int lr_ = (wc & 1) * 64 + ((NH) * 2 + j_) * 16 + fr;                    \
            _Pragma("unroll")                                                             \
            for (int ks_ = 0; ks_ < 2; ++ks_)                                             \
                bg[NH][j_][ks_] = *(const bf16x8*)&r_[lr_ * 64 + (((ks_ * 4 + fq) ^ (fr & 7)) * 8)]; \
        }                                                                                 \
    } while (0)

#define MFMA16(MH, NH)                                                                    \
    do {                                                                                  \
        __builtin_amdgcn_s_setprio(1);                                                    \
        _Pragma("unroll")                                                                 \
        for (int q_ = 0; q_ < 4; ++q_)                                                    \
            _Pragma("unroll")                                                             \
            for (int j_ = 0; j_ < 2; ++j_) {                                              \
                acc[(MH) * 4 + q_][(NH) * 2 + j_] = __builtin_amdgcn_mfma_f32_16x16x32_bf16( \
                    af[MH][q_][0], bg[NH][j_][0], acc[(MH) * 4 + q_][(NH) * 2 + j_], 0, 0, 0); \
                acc[(MH) * 4 + q_][(NH) * 2 + j_] = __builtin_amdgcn_mfma_f32_16x16x32_bf16( \
                    af[MH][q_][1], bg[NH][j_][1], acc[(MH) * 4 + q_][(NH) * 2 + j_], 0, 0, 0); \
            }                                                                             \
        __builtin_amdgcn_s_setprio(0);                                                    \
    } while (0)

    STAGE_HALF(Bt, n0, 0, 0, 1, 0);
    STAGE_HALF(Bt, n0, 0, 0, 1, 1);
    STAGE_HALF(A,  m0, 0, 0, 0, 0);
    STAGE_HALF(A,  m0, 0, 0, 0, 1);
    STAGE_HALF(Bt, n0, 1, 1, 1, 0);
    VMC0;
    BAR;

    for (int i = 0; i < 8; ++i) {
        const int t_b1cur = 2 * i + 1;
        const int t_b0nxt = 2 * i + 2;
        const int t_b1nxt = 2 * i + 3;
        READ_AF(0, 0); READ_BG(0, 0);
        STAGE_HALF(Bt, n0, t_b1cur, 1, 1, 1);
        BAR; LGKM0; MFMA16(0, 0); BAR;
        READ_BG(0, 1);
        STAGE_HALF(A, m0, t_b1cur, 1, 0, 0);
        BAR; LGKM0; MFMA16(0, 1); BAR;
        READ_AF(0, 1);
        STAGE_HALF(A, m0, t_b1cur, 1, 0, 1);
        BAR; LGKM0; MFMA16(1, 0); BAR;
        VMC0;
        if (t_b0nxt < 16) STAGE_HALF(Bt, n0, t_b0nxt, 0, 1, 0);
        BAR; MFMA16(1, 1); BAR;
        READ_AF(1, 0); READ_BG(1, 0);
        if (t_b0nxt < 16) STAGE_HALF(Bt, n0, t_b0nxt, 0, 1, 1);
        BAR; LGKM0; MFMA16(0, 0); BAR;
        READ_BG(1, 1);
        if (t_b0nxt < 16) STAGE_HALF(A, m0, t_b0nxt, 0, 0, 0);
        BAR; LGKM0; MFMA16(0, 1); BAR;
        READ_AF(1, 1);
        if (t_b0nxt < 16) STAGE_HALF(A, m0, t_b0nxt, 0, 0, 1);
        BAR; LGKM0; MFMA16(1, 0); BAR;
        VMC0;
        if (t_b1nxt < 16) STAGE_HALF(Bt, n0, t_b1nxt, 1, 1, 0);
        BAR; MFMA16(1, 1); BAR;
    }

#undef VMC0
#undef LGKM0
#undef BAR
#undef STAGE_HALF
#undef READ_AF
#undef READ_BG
#undef MFMA16

#pragma unroll
    for (int ni = 0; ni < 4; ++ni) {
        const int col = n0 + wc * 64 + ni * 16 + fr;
        const float bias = by[col];
#pragma unroll
        for (int mi = 0; mi < 8; ++mi) {
            const int row = m0 + wr * 128 + mi * 16 + fq * 4;
            float* cp = C + (size_t)row * VOCAB + col;
            cp[0]                 = acc[mi][ni][0] + bias;
            cp[(size_t)VOCAB]     = acc[mi][ni][1] + bias;
            cp[(size_t)2 * VOCAB] = acc[mi][ni][2] + bias;
            cp[(size_t)3 * VOCAB] = acc[mi][ni][3] + bias;
        }
    }
}

extern "C" void kernel_launch(void* const* d_in, const int* in_sizes, int n_in,
                              void* d_out, int out_size, void* d_ws, size_t ws_size,
                              hipStream_t stream) {
    const int*   x   = (const int*)d_in[0];
    const float* emb = (const float*)d_in[1];
    const float* Wxh = (const float*)d_in[2];
    const float* Whh = (const float*)d_in[3];
    const float* bh  = (const float*)d_in[4];
    const float* Why = (const float*)d_in[5];
    const float* by  = (const float*)d_in[6];
    float* y = (float*)d_out;

    char* ws = (char*)d_ws;
    const size_t off_xh = 0;
    const size_t off_hx = off_xh + (size_t)NB * NT * HIDDEN * 4;
    const size_t off_hs = off_hx + (size_t)NCH * 2 * 512 * 8;
    const size_t off_wt = off_hs + (size_t)NB * NT * HIDDEN * 2;
    const size_t need   = off_wt + (size_t)VOCAB * HIDDEN * 2;
    if (ws_size < need) return;

    float* xh = (float*)(ws + off_xh);
    unsigned long long* hx = (unsigned long long*)(ws + off_hx);
    __hip_bfloat16* hs = (__hip_bfloat16*)(ws + off_hs);
    __hip_bfloat16* Wt = (__hip_bfloat16*)(ws + off_wt);

    k_xh<<<dim3((NB * NT) / XH_ROWS), 256, 0, stream>>>(x, emb, Wxh, bh, xh);
    k_fused<<<dim3(NBLK_REC + NBLK_TR), 256, 0, stream>>>(Whh, xh, hx, hs, Why, Wt);
    k_proj<<<dim3((2048 / 256) * (VOCAB / 256)), 512, 0, stream>>>((const unsigned short*)hs,
                                                                   (const unsigned short*)Wt, by, y);
}